// Round 4
// baseline (144104.871 us; speedup 1.0000x reference)
//
#include <hip/hip_runtime.h>
#include <math.h>

#define T_STEPS 20000
#define RSIZE   2048
#define ISIZE   128
#define NBLK    64
#define NTHR    512                    // 8 waves/block, 1 block/CU
#define RPW     4                      // rows per wave (2048 / (64*8))
#define FSTRIDE 16                     // flag spacing: 16 dwords = 64 B

// ---- cheap erf: Abramowitz-Stegun 7.1.26, |err| <= 1.5e-7 (abs) ----
__device__ __forceinline__ float erf_approx(float x) {
    float ax = fabsf(x);
    float t  = 1.0f / (1.0f + 0.3275911f * ax);
    float y  = t * (0.254829592f +
               t * (-0.284496736f +
               t * (1.421413741f +
               t * (-1.453152027f +
               t * 1.061405429f))));
    float e  = __expf(-ax * ax);
    float r  = 1.0f - y * e;
    return copysignf(r, x);
}

// ---- explicit AGPR residency (gfx950 unified RF; no MFMA in this kernel) ----
#define AGPR_W(a, v) asm volatile("v_accvgpr_write_b32 %0, %1" : "=a"(a) : "v"(v))
#define AGPR_R(v, a) asm volatile("v_accvgpr_read_b32 %0, %1" : "=v"(v) : "a"(a))

__global__ __launch_bounds__(NTHR, 2) void esn_persistent(
        const float* __restrict__ input,   // [T, 128]
        const float* __restrict__ W_in,    // [2048, 128]
        const float* __restrict__ W_res,   // [2048, 2048]
        float* __restrict__ out,           // [T, 2048]  (rows == states)
        unsigned* __restrict__ flags) {    // 64 flags, 64B apart, monotonic
    const int tid  = threadIdx.x;
    const int lane = tid & 63;
    const int wv   = tid >> 6;
    const int wid  = blockIdx.x * (NTHR / 64) + wv;
    const int r0   = wid * RPW;
    const float invs = 0.022097086912079608f;  // 1/sqrt(2048)

    // ---- load W once, park it in AGPRs ----
    // W_res row r, lane l holds cols {c*256 + l*4 .. +3 : c=0..7}  (32 f32)
    float a_w[RPW][32];
    float a_wi[RPW][2];
#pragma unroll
    for (int m = 0; m < RPW; ++m) {
        const float* row = W_res + (size_t)(r0 + m) * RSIZE;
#pragma unroll
        for (int c = 0; c < 8; ++c) {
            float4 w = *(const float4*)(row + c * 256 + lane * 4);
            AGPR_W(a_w[m][c * 4 + 0], w.x);
            AGPR_W(a_w[m][c * 4 + 1], w.y);
            AGPR_W(a_w[m][c * 4 + 2], w.z);
            AGPR_W(a_w[m][c * 4 + 3], w.w);
        }
        float2 wiv = *(const float2*)(W_in + (size_t)(r0 + m) * ISIZE + lane * 2);
        AGPR_W(a_wi[m][0], wiv.x);
        AGPR_W(a_wi[m][1], wiv.y);
    }

    unsigned* myflag   = flags + blockIdx.x * FSTRIDE;
    unsigned* pollflag = flags + lane * FSTRIDE;

    for (int t = 0; t < T_STEPS; ++t) {
        // ---- input projection first: independent of other blocks ----
        float2 uv = ((const float2*)(input + (size_t)t * ISIZE))[lane];
        float base[RPW];
#pragma unroll
        for (int m = 0; m < RPW; ++m) {
            float w0, w1;
            AGPR_R(w0, a_wi[m][0]);
            AGPR_R(w1, a_wi[m][1]);
            base[m] = w0 * uv.x + w1 * uv.y;
        }

        // ---- wait for x[t-1]: one flag per lane, single release hop ----
        float4 xv[8];
        float  xp = 0.0f;
        if (t > 0) {
            const unsigned want = (unsigned)t;
            while (true) {
                unsigned f = __hip_atomic_load(pollflag, __ATOMIC_RELAXED,
                                               __HIP_MEMORY_SCOPE_AGENT);
                if (__all((int)(f >= want))) break;
                __builtin_amdgcn_s_sleep(1);
            }
            __builtin_amdgcn_fence(__ATOMIC_ACQUIRE, "agent");
            const float* xprev = out + (size_t)(t - 1) * RSIZE;
#pragma unroll
            for (int c = 0; c < 8; ++c)
                xv[c] = ((const float4*)xprev)[c * 64 + lane];
            if (lane < RPW) xp = xprev[r0 + lane];
        } else {
#pragma unroll
            for (int c = 0; c < 8; ++c)
                xv[c] = make_float4(0.f, 0.f, 0.f, 0.f);
        }

        // ---- per-wave matvec rows r0..r0+3, W streamed from AGPRs ----
        float acc[RPW];
#pragma unroll
        for (int m = 0; m < RPW; ++m) {
            float s0 = base[m];
            float s1 = 0.0f;
#pragma unroll
            for (int c = 0; c < 8; ++c) {
                float t0, t1, t2, t3;
                AGPR_R(t0, a_w[m][c * 4 + 0]);
                AGPR_R(t1, a_w[m][c * 4 + 1]);
                AGPR_R(t2, a_w[m][c * 4 + 2]);
                AGPR_R(t3, a_w[m][c * 4 + 3]);
                s0 = fmaf(t0, xv[c].x, s0);
                s1 = fmaf(t1, xv[c].y, s1);
                s0 = fmaf(t2, xv[c].z, s0);
                s1 = fmaf(t3, xv[c].w, s1);
            }
            float a = s0 + s1;
#pragma unroll
            for (int off = 32; off > 0; off >>= 1)
                a += __shfl_xor(a, off, 64);
            acc[m] = a;   // every lane holds the full row sum
        }

        // lanes 0..3 each finish one row (static acc indexing)
        if (lane < RPW) {
            float pre = (lane == 0) ? acc[0]
                      : (lane == 1) ? acc[1]
                      : (lane == 2) ? acc[2] : acc[3];
            float xn  = 0.1f * xp + 0.9f * erf_approx(pre) * invs;
            out[(size_t)t * RSIZE + r0 + lane] = xn;
        }

        // ---- publish: all 8 waves' stores done -> one release flag ----
        __syncthreads();
        if (tid == 0) {
            __hip_atomic_store(myflag, (unsigned)(t + 1), __ATOMIC_RELEASE,
                               __HIP_MEMORY_SCOPE_AGENT);
        }
    }
}

extern "C" void kernel_launch(void* const* d_in, const int* in_sizes, int n_in,
                              void* d_out, int out_size, void* d_ws,
                              size_t ws_size, hipStream_t stream) {
    const float* input = (const float*)d_in[0];
    const float* W_in  = (const float*)d_in[1];
    const float* W_res = (const float*)d_in[2];
    float*       out   = (float*)d_out;
    unsigned*    flags = (unsigned*)d_ws;

    // flags must be zero at the start of every call (deterministic)
    hipMemsetAsync(flags, 0, NBLK * FSTRIDE * sizeof(unsigned), stream);

    void* args[] = {(void*)&input, (void*)&W_in, (void*)&W_res,
                    (void*)&out, (void*)&flags};
    hipError_t err = hipLaunchCooperativeKernel(
        (const void*)esn_persistent, dim3(NBLK), dim3(NTHR), args, 0, stream);
    if (err != hipSuccess) {
        // 64 blocks / 256 CUs: trivially co-resident; plain launch fallback
        esn_persistent<<<dim3(NBLK), dim3(NTHR), 0, stream>>>(
            input, W_in, W_res, out, flags);
    }
}

// Round 5
// 61865.973 us; speedup vs baseline: 2.3293x; 2.3293x over previous
//
#include <hip/hip_runtime.h>
#include <math.h>

#define T_STEPS 20000
#define RSIZE   2048
#define ISIZE   128
#define NBLK    64
#define NTHR    512                    // 8 waves/block, 1 block/CU
#define RPW     4                      // rows per wave (2048 / (64*8))
#define FSTRIDE 16                     // flag spacing: 16 dwords = 64 B

// ---- cheap erf: Abramowitz-Stegun 7.1.26, |err| <= 1.5e-7 (abs) ----
__device__ __forceinline__ float erf_approx(float x) {
    float ax = fabsf(x);
    float t  = 1.0f / (1.0f + 0.3275911f * ax);
    float y  = t * (0.254829592f +
               t * (-0.284496736f +
               t * (1.421413741f +
               t * (-1.453152027f +
               t * 1.061405429f))));
    float e  = __expf(-ax * ax);
    float r  = 1.0f - y * e;
    return copysignf(r, x);
}

// ---- explicit AGPR residency (gfx950 unified RF; no MFMA in this kernel) ----
#define AGPR_W(a, v) asm volatile("v_accvgpr_write_b32 %0, %1" : "=a"(a) : "v"(v))
#define AGPR_R(v, a) asm volatile("v_accvgpr_read_b32 %0, %1" : "=v"(v) : "a"(a))

// ---- device-coherent (L3-point) accesses: no cache-wide fence ops needed ----
__device__ __forceinline__ unsigned ld_coh_u32(const unsigned* p) {
    unsigned r;
    asm volatile("global_load_dword %0, %1, off sc0 sc1\n\ts_waitcnt vmcnt(0)"
                 : "=v"(r) : "v"(p) : "memory");
    return r;
}
__device__ __forceinline__ float4 ld_coh_f4(const float* p) {
    float4 r;
    asm volatile("global_load_dwordx4 %0, %1, off sc0 sc1\n\ts_waitcnt vmcnt(0)"
                 : "=v"(r) : "v"(p) : "memory");
    return r;
}
__device__ __forceinline__ void st_coh_f32(float* p, float v) {
    asm volatile("global_store_dword %0, %1, off sc0 sc1"
                 :: "v"(p), "v"(v) : "memory");
}
__device__ __forceinline__ void st_coh_u32(unsigned* p, unsigned v) {
    asm volatile("global_store_dword %0, %1, off sc0 sc1"
                 :: "v"(p), "v"(v) : "memory");
}

__global__ __launch_bounds__(NTHR, 2) void esn_persistent(
        const float* __restrict__ input,   // [T, 128]
        const float* __restrict__ W_in,    // [2048, 128]
        const float* __restrict__ W_res,   // [2048, 2048]
        float* __restrict__ out,           // [T, 2048]  (rows == states)
        unsigned* __restrict__ flags) {    // 64 monotonic flags, 64B apart
    __shared__ float xbuf[RSIZE];

    const int tid  = threadIdx.x;
    const int lane = tid & 63;
    const int wv   = tid >> 6;
    const int wid  = blockIdx.x * (NTHR / 64) + wv;
    const int r0   = wid * RPW;
    const float invs = 0.022097086912079608f;  // 1/sqrt(2048)

    // ---- load W once, park it in AGPRs ----
    // W_res row r, lane l holds cols {c*256 + l*4 .. +3 : c=0..7}  (32 f32)
    float a_w[RPW][32];
    float a_wi[RPW][2];
#pragma unroll
    for (int m = 0; m < RPW; ++m) {
        const float* row = W_res + (size_t)(r0 + m) * RSIZE;
#pragma unroll
        for (int c = 0; c < 8; ++c) {
            float4 w = *(const float4*)(row + c * 256 + lane * 4);
            AGPR_W(a_w[m][c * 4 + 0], w.x);
            AGPR_W(a_w[m][c * 4 + 1], w.y);
            AGPR_W(a_w[m][c * 4 + 2], w.z);
            AGPR_W(a_w[m][c * 4 + 3], w.w);
        }
        float2 wiv = *(const float2*)(W_in + (size_t)(r0 + m) * ISIZE + lane * 2);
        AGPR_W(a_wi[m][0], wiv.x);
        AGPR_W(a_wi[m][1], wiv.y);
    }

    unsigned*       myflag   = flags + blockIdx.x * FSTRIDE;
    const unsigned* pollflag = flags + lane * FSTRIDE;

    for (int t = 0; t < T_STEPS; ++t) {
        // ---- input projection first: independent of other blocks ----
        float2 uv = ((const float2*)(input + (size_t)t * ISIZE))[lane];
        float base[RPW];
#pragma unroll
        for (int m = 0; m < RPW; ++m) {
            float w0, w1;
            AGPR_R(w0, a_wi[m][0]);
            AGPR_R(w1, a_wi[m][1]);
            base[m] = w0 * uv.x + w1 * uv.y;
        }

        // ---- wait for x[t-1] (wave 0 polls), stage it through LDS ----
        float4 xv[8];
        float  xp = 0.0f;
        if (t > 0) {
            if (wv == 0) {
                const unsigned want = (unsigned)t;
                while (true) {
                    unsigned f = ld_coh_u32(pollflag);
                    if (__all((int)(f >= want))) break;
                    __builtin_amdgcn_s_sleep(1);
                }
            }
            __syncthreads();
            const float* xprev = out + (size_t)(t - 1) * RSIZE;
            ((float4*)xbuf)[tid] = ld_coh_f4(xprev + tid * 4);
            __syncthreads();
#pragma unroll
            for (int c = 0; c < 8; ++c)
                xv[c] = ((const float4*)xbuf)[c * 64 + lane];
            if (lane < RPW) xp = xbuf[r0 + lane];
        } else {
#pragma unroll
            for (int c = 0; c < 8; ++c)
                xv[c] = make_float4(0.f, 0.f, 0.f, 0.f);
        }

        // ---- per-wave matvec rows r0..r0+3, W streamed from AGPRs ----
        float acc[RPW];
#pragma unroll
        for (int m = 0; m < RPW; ++m) {
            float s0 = base[m];
            float s1 = 0.0f;
#pragma unroll
            for (int c = 0; c < 8; ++c) {
                float t0, t1, t2, t3;
                AGPR_R(t0, a_w[m][c * 4 + 0]);
                AGPR_R(t1, a_w[m][c * 4 + 1]);
                AGPR_R(t2, a_w[m][c * 4 + 2]);
                AGPR_R(t3, a_w[m][c * 4 + 3]);
                s0 = fmaf(t0, xv[c].x, s0);
                s1 = fmaf(t1, xv[c].y, s1);
                s0 = fmaf(t2, xv[c].z, s0);
                s1 = fmaf(t3, xv[c].w, s1);
            }
            float a = s0 + s1;
#pragma unroll
            for (int off = 32; off > 0; off >>= 1)
                a += __shfl_xor(a, off, 64);
            acc[m] = a;   // every lane holds the full row sum
        }

        // lanes 0..3 each finish one row; write-through to coherence point
        if (lane < RPW) {
            float pre = (lane == 0) ? acc[0]
                      : (lane == 1) ? acc[1]
                      : (lane == 2) ? acc[2] : acc[3];
            float xn  = 0.1f * xp + 0.9f * erf_approx(pre) * invs;
            st_coh_f32(out + (size_t)t * RSIZE + r0 + lane, xn);
        }
        // drain own stores to L3, then publish the block's flag
        asm volatile("s_waitcnt vmcnt(0)" ::: "memory");
        __syncthreads();
        if (tid == 0)
            st_coh_u32(myflag, (unsigned)(t + 1));
    }
}

extern "C" void kernel_launch(void* const* d_in, const int* in_sizes, int n_in,
                              void* d_out, int out_size, void* d_ws,
                              size_t ws_size, hipStream_t stream) {
    const float* input = (const float*)d_in[0];
    const float* W_in  = (const float*)d_in[1];
    const float* W_res = (const float*)d_in[2];
    float*       out   = (float*)d_out;
    unsigned*    flags = (unsigned*)d_ws;

    // flags must be zero at the start of every call (deterministic)
    hipMemsetAsync(flags, 0, NBLK * FSTRIDE * sizeof(unsigned), stream);

    void* args[] = {(void*)&input, (void*)&W_in, (void*)&W_res,
                    (void*)&out, (void*)&flags};
    hipError_t err = hipLaunchCooperativeKernel(
        (const void*)esn_persistent, dim3(NBLK), dim3(NTHR), args, 0, stream);
    if (err != hipSuccess) {
        // 64 blocks / 256 CUs: trivially co-resident; plain launch fallback
        esn_persistent<<<dim3(NBLK), dim3(NTHR), 0, stream>>>(
            input, W_in, W_res, out, flags);
    }
}